// Round 5
// baseline (247.580 us; speedup 1.0000x reference)
//
#include <hip/hip_runtime.h>
#include <hip/hip_bf16.h>

typedef __attribute__((ext_vector_type(8))) short bf16x8;
typedef __attribute__((ext_vector_type(4))) float f32x4;

#define MARGIN 0.3f
#define BIGF 3.0e38f

// Wave-per-row convert: fp32 -> bf16 cast, fp32 row norm (of the
// bf16-rounded values, consistent with MFMA dots), init ap/an/cnt.
__global__ __launch_bounds__(256) void convert_norm_kernel(
    const float* __restrict__ X, __hip_bfloat16* __restrict__ Xb,
    float* __restrict__ nrm, unsigned* __restrict__ ap,
    unsigned* __restrict__ an, unsigned* __restrict__ cnt, int K) {
    const int wave = threadIdx.x >> 6, lane = threadIdx.x & 63;
    const int row = blockIdx.x * 4 + wave;
    const float* xr = X + (size_t)row * K;
    __hip_bfloat16* xbr = Xb + (size_t)row * K;
    float s = 0.0f;
    for (int c = lane * 4; c < K; c += 64 * 4) {
        float4 v = *(const float4*)(xr + c);
        union { __hip_bfloat16 h[4]; uint2 u; } p;
        p.h[0] = __float2bfloat16(v.x);
        p.h[1] = __float2bfloat16(v.y);
        p.h[2] = __float2bfloat16(v.z);
        p.h[3] = __float2bfloat16(v.w);
        *(uint2*)(xbr + c) = p.u;
        float f0 = __bfloat162float(p.h[0]);
        float f1 = __bfloat162float(p.h[1]);
        float f2 = __bfloat162float(p.h[2]);
        float f3 = __bfloat162float(p.h[3]);
        s += f0 * f0 + f1 * f1 + f2 * f2 + f3 * f3;
    }
    for (int off = 32; off > 0; off >>= 1) s += __shfl_xor(s, off, 64);
    if (lane == 0) {
        nrm[row] = s;
        ap[row] = 0u;           // dist_ap >= 0 always (self is a positive)
        an[row] = 0x7F800000u;  // +inf
        if (row == 0) *cnt = 0u;
    }
}

// Barrier-free K-loop: both MFMA operands of G = Xb*Xb^T are 16 contiguous
// bytes of an Xb row (A[row][k..k+7], B[col][k..k+7]), so fragments load
// DIRECTLY from global (L2-resident, 16 MB) as global_load_dwordx4 — no LDS
// staging, no __syncthreads, no vmcnt(0) drain (the R3/R4 serialization).
// Upper-triangle 64x128 tiles (1056 blocks), 2 waves/block, each wave owns
// 64 rows x 64 cols = 4x4 16x16x32 subtiles (16 MFMA per 8 loads/k-step).
// Depth-1 register prefetch + 3 waves/SIMD hide L2 latency.
// Epilogue reduces rows (cross-wave via LDS) and cols (wave-local) into
// global ap/an via monotone uint atomics; LAST block computes the loss.
__global__ __launch_bounds__(128, 3) void gemm_reduce_kernel(
    const __hip_bfloat16* __restrict__ Xb, const float* __restrict__ nrm,
    const int* __restrict__ Y, unsigned* __restrict__ ap,
    unsigned* __restrict__ an, unsigned* __restrict__ cnt,
    float* __restrict__ out, int N, int K) {
    __shared__ int sYr[64], sYc[128];
    __shared__ float sNr[64], sNc[128];
    __shared__ float redmax[2][64], redmin[2][64];
    __shared__ float lsum[2];
    __shared__ unsigned s_done;

    const int tid = threadIdx.x;
    const int wave = tid >> 6;
    const int lane = tid & 63;
    const int q = lane >> 4;   // quad within wave (k-chunk selector)
    const int lc = lane & 15;  // row/col within 16x16 subtile

    // Decode (col-block j, row-block r): blocks for col j are j(j+1)..(j+1)(j+2).
    int j = 0;
    {
        const int b = blockIdx.x;
        while ((j + 1) * (j + 2) <= b) j++;
    }
    const int r = blockIdx.x - j * (j + 1);  // 0..2j+1
    const int rowBase = r * 64;
    const int colBase = j * 128;

    if (tid < 64) {
        sYr[tid] = Y[rowBase + tid];
        sNr[tid] = nrm[rowBase + tid];
    }
    sYc[tid] = Y[colBase + tid];
    sNc[tid] = nrm[colBase + tid];

    f32x4 acc[4][4];
#pragma unroll
    for (int i = 0; i < 4; i++)
#pragma unroll
        for (int jj = 0; jj < 4; jj++) acc[i][jj] = (f32x4){0.f, 0.f, 0.f, 0.f};

    // Fragment layout (16x16x32): lane holds M[row=lc][k = q*8 + 0..7].
    // Per-lane base pointers; subtile s adds s*16 rows; k advances uniformly.
    const __hip_bfloat16* aP = Xb + (size_t)(rowBase + lc) * K + q * 8;
    const __hip_bfloat16* bP = Xb + (size_t)(colBase + wave * 64 + lc) * K + q * 8;
    const size_t sK = (size_t)16 * K;  // subtile row stride, elements

#define LOADF(dst, base, k)                                   \
    {                                                         \
        _Pragma("unroll") for (int s = 0; s < 4; s++)         \
            dst[s] = *(const bf16x8*)((base) + (k) + s * sK); \
    }
#define MFMA16(af, bf)                                                        \
    {                                                                         \
        _Pragma("unroll") for (int si = 0; si < 4; si++)                      \
            _Pragma("unroll") for (int sj = 0; sj < 4; sj++)                  \
                acc[si][sj] = __builtin_amdgcn_mfma_f32_16x16x32_bf16(        \
                    af[si], bf[sj], acc[si][sj], 0, 0, 0);                    \
    }

    bf16x8 a0[4], b0[4], a1[4], b1[4];
    LOADF(a0, aP, 0);
    LOADF(b0, bP, 0);
    // K multiple of 64; steps of 32 (one MFMA16 each), unrolled x2 with
    // depth-1 prefetch. No barriers anywhere in this loop.
    int k = 0;
    for (; k + 64 < K; k += 64) {
        LOADF(a1, aP, k + 32);
        LOADF(b1, bP, k + 32);
        MFMA16(a0, b0);
        LOADF(a0, aP, k + 64);
        LOADF(b0, bP, k + 64);
        MFMA16(a1, b1);
    }
    LOADF(a1, aP, k + 32);
    LOADF(b1, bP, k + 32);
    MFMA16(a0, b0);
    MFMA16(a1, b1);

    __syncthreads();  // sY*/sN* fill visible (first and only pre-epilogue sync)

    // Epilogue. C/D layout: col = lc, row = q*4 + reg (within subtile).
    float rmx[4][4], rmn[4][4];
    float cmx[4], cmn[4];
#pragma unroll
    for (int i = 0; i < 4; i++) {
        cmx[i] = -1.0f; cmn[i] = BIGF;
#pragma unroll
        for (int rr = 0; rr < 4; rr++) { rmx[i][rr] = -1.0f; rmn[i][rr] = BIGF; }
    }

#pragma unroll
    for (int sj = 0; sj < 4; sj++) {
        const int ct = wave * 64 + sj * 16 + lc;
        const int yc = sYc[ct];
        const float nc = sNc[ct];
#pragma unroll
        for (int si = 0; si < 4; si++) {
            const int rbase = si * 16 + q * 4;
#pragma unroll
            for (int rr = 0; rr < 4; rr++) {
                const int rt = rbase + rr;
                float d2 = sNr[rt] + nc - 2.0f * acc[si][sj][rr];
                float d = sqrtf(fmaxf(d2, 0.0f));
                bool same = (sYr[rt] == yc);
                float dp = same ? d : -1.0f;
                float dn = same ? BIGF : d;
                rmx[si][rr] = fmaxf(rmx[si][rr], dp);
                rmn[si][rr] = fminf(rmn[si][rr], dn);
                cmx[sj] = fmaxf(cmx[sj], dp);
                cmn[sj] = fminf(cmn[sj], dn);
            }
        }
    }

    // Row-side: butterfly across the 16 lanes of a quad (same row, 16 cols).
#pragma unroll
    for (int si = 0; si < 4; si++)
#pragma unroll
        for (int rr = 0; rr < 4; rr++) {
            float mx = rmx[si][rr], mn = rmn[si][rr];
            for (int off = 1; off < 16; off <<= 1) {
                mx = fmaxf(mx, __shfl_xor(mx, off, 64));
                mn = fminf(mn, __shfl_xor(mn, off, 64));
            }
            if (lc == 0) {
                redmax[wave][si * 16 + q * 4 + rr] = mx;
                redmin[wave][si * 16 + q * 4 + rr] = mn;
            }
        }

    // Col-side: wave-local — reduce across quads (rows) via xor 16/32, then
    // q==0 lanes hold col sj*16+lc; atomic directly (non-negative floats:
    // uint cmp == float cmp; clamp max to 0 since true dist_ap >= 0).
#pragma unroll
    for (int sj = 0; sj < 4; sj++) {
        float mx = cmx[sj], mn = cmn[sj];
        mx = fmaxf(mx, __shfl_xor(mx, 16, 64));
        mn = fminf(mn, __shfl_xor(mn, 16, 64));
        mx = fmaxf(mx, __shfl_xor(mx, 32, 64));
        mn = fminf(mn, __shfl_xor(mn, 32, 64));
        if (q == 0) {
            const int c = colBase + wave * 64 + sj * 16 + lc;
            atomicMax(&ap[c], __float_as_uint(fmaxf(mx, 0.0f)));
            atomicMin(&an[c], __float_as_uint(mn));
        }
    }
    __syncthreads();

    if (tid < 64) {
        float mx = fmaxf(redmax[0][tid], redmax[1][tid]);
        float mn = fminf(redmin[0][tid], redmin[1][tid]);
        atomicMax(&ap[rowBase + tid], __float_as_uint(fmaxf(mx, 0.0f)));
        atomicMin(&an[rowBase + tid], __float_as_uint(mn));
    }

    // Last block computes the loss (release fence before counter increment;
    // acquire fence + agent-scope atomic loads in the last block).
    __syncthreads();
    if (tid == 0) {
        __threadfence();
        s_done = atomicAdd(cnt, 1u);
    }
    __syncthreads();
    if (s_done == gridDim.x - 1) {
        __threadfence();
        float s = 0.0f;
        for (int i = tid; i < N; i += 128) {
            unsigned ua = __hip_atomic_load(&ap[i], __ATOMIC_RELAXED,
                                            __HIP_MEMORY_SCOPE_AGENT);
            unsigned ub = __hip_atomic_load(&an[i], __ATOMIC_RELAXED,
                                            __HIP_MEMORY_SCOPE_AGENT);
            s += fmaxf(__uint_as_float(ua) - __uint_as_float(ub) + MARGIN, 0.0f);
        }
        for (int off = 32; off > 0; off >>= 1) s += __shfl_xor(s, off, 64);
        if (lane == 0) lsum[wave] = s;
        __syncthreads();
        if (tid == 0) out[0] = (lsum[0] + lsum[1]) / (float)N;
    }
}

extern "C" void kernel_launch(void* const* d_in, const int* in_sizes, int n_in,
                              void* d_out, int out_size, void* d_ws, size_t ws_size,
                              hipStream_t stream) {
    const float* X = (const float*)d_in[0];
    const int* Y = (const int*)d_in[1];
    float* out = (float*)d_out;
    const int N = in_sizes[1];          // 4096
    const int K = in_sizes[0] / N;      // 2048

    char* ws = (char*)d_ws;
    __hip_bfloat16* Xb = (__hip_bfloat16*)ws;                       // N*K*2 bytes
    float* nrm = (float*)(ws + (size_t)N * K * sizeof(__hip_bfloat16));
    unsigned* ap = (unsigned*)((char*)nrm + (size_t)N * 4);
    unsigned* an = (unsigned*)((char*)ap + (size_t)N * 4);
    unsigned* cnt = (unsigned*)((char*)an + (size_t)N * 4);

    convert_norm_kernel<<<N / 4, 256, 0, stream>>>(X, Xb, nrm, ap, an, cnt, K);
    const int NB = N / 128;
    const int nblocks = NB * (NB + 1);  // 64x128 tiles covering the triangle
    gemm_reduce_kernel<<<nblocks, 128, 0, stream>>>(Xb, nrm, Y, ap, an, cnt,
                                                    out, N, K);
}

// Round 6
// 206.559 us; speedup vs baseline: 1.1986x; 1.1986x over previous
//
#include <hip/hip_runtime.h>
#include <hip/hip_bf16.h>

typedef __attribute__((ext_vector_type(8))) short bf16x8;
typedef __attribute__((ext_vector_type(4))) float f32x4;

#define MARGIN 0.3f
#define BIGF 3.0e38f

__device__ __forceinline__ void gl2lds16(const void* g, void* l) {
    __builtin_amdgcn_global_load_lds(
        (const __attribute__((address_space(1))) void*)g,
        (__attribute__((address_space(3))) void*)l,
        16, 0, 0);
}

// Wave-per-row convert: fp32 -> bf16 cast, fp32 row norm (of the
// bf16-rounded values, consistent with MFMA dots), init ap/an/cnt.
__global__ __launch_bounds__(256) void convert_norm_kernel(
    const float* __restrict__ X, __hip_bfloat16* __restrict__ Xb,
    float* __restrict__ nrm, unsigned* __restrict__ ap,
    unsigned* __restrict__ an, unsigned* __restrict__ cnt, int K) {
    const int wave = threadIdx.x >> 6, lane = threadIdx.x & 63;
    const int row = blockIdx.x * 4 + wave;
    const float* xr = X + (size_t)row * K;
    __hip_bfloat16* xbr = Xb + (size_t)row * K;
    float s = 0.0f;
    for (int c = lane * 4; c < K; c += 64 * 4) {
        float4 v = *(const float4*)(xr + c);
        union { __hip_bfloat16 h[4]; uint2 u; } p;
        p.h[0] = __float2bfloat16(v.x);
        p.h[1] = __float2bfloat16(v.y);
        p.h[2] = __float2bfloat16(v.z);
        p.h[3] = __float2bfloat16(v.w);
        *(uint2*)(xbr + c) = p.u;
        float f0 = __bfloat162float(p.h[0]);
        float f1 = __bfloat162float(p.h[1]);
        float f2 = __bfloat162float(p.h[2]);
        float f3 = __bfloat162float(p.h[3]);
        s += f0 * f0 + f1 * f1 + f2 * f2 + f3 * f3;
    }
    for (int off = 32; off > 0; off >>= 1) s += __shfl_xor(s, off, 64);
    if (lane == 0) {
        nrm[row] = s;
        ap[row] = 0u;           // dist_ap >= 0 always (self is a positive)
        an[row] = 0x7F800000u;  // +inf
        if (row == 0) *cnt = 0u;
    }
}

// WAVE-PRIVATE tiles, ZERO barriers in the K-loop. Each wave owns one
// 64x64 upper-triangle tile (2080 tiles at N=4096; 2 waves/block = 1040
// blocks), stages its own A(64 rows) + B(64 cols) via gl2lds into its own
// 32 KB LDS region, double-buffered with per-wave `s_waitcnt vmcnt(16)`:
// the 16 just-issued next-tile loads stay in flight while tile t computes.
// No cross-wave coupling -> no lockstep stalls (the R3 ceiling). Proven
// pieces: 128B-row XOR swizzle (0 conflicts, R2/R3), 16x16x32 fragment
// layout (exact, R1-R5). Epilogue is fully wave-local: row-side and
// col-side reductions via shfl, monotone uint atomics to global ap/an;
// diagonal tiles double-update idempotently. LAST block computes the loss.
__global__ __launch_bounds__(128) void gemm_reduce_kernel(
    const __hip_bfloat16* __restrict__ Xb, const float* __restrict__ nrm,
    const int* __restrict__ Y, unsigned* __restrict__ ap,
    unsigned* __restrict__ an, unsigned* __restrict__ cnt,
    float* __restrict__ out, int N, int K) {
    // Per wave: [A buf0 8K][A buf1 8K][B buf0 8K][B buf1 8K] = 32 KB.
    __shared__ __align__(16) char sMem[2][32768];
    __shared__ float lsum[2];
    __shared__ unsigned s_done;

    const int tid = threadIdx.x;
    const int wave = tid >> 6;
    const int lane = tid & 63;
    const int q = lane >> 4;   // quad within wave
    const int lc = lane & 15;  // col within 16x16 subtile

    // Tile for THIS wave: linear upper-triangle index (64x64 granularity).
    const int NB = N >> 6;
    const int ntiles = NB * (NB + 1) / 2;
    int t = blockIdx.x * 2 + wave;
    if (t >= ntiles) t = ntiles - 1;  // duplicate work; idempotent updates
    int ib = 0, rem = t;
    while (rem >= NB - ib) { rem -= NB - ib; ib++; }
    const int rowB = ib * 64;
    const int colB = (ib + rem) * 64;

    f32x4 acc[4][4];
#pragma unroll
    for (int i = 0; i < 4; i++)
#pragma unroll
        for (int jj = 0; jj < 4; jj++) acc[i][jj] = (f32x4){0.f, 0.f, 0.f, 0.f};

    // Staging (per wave, all 64 rows of each operand): lane l -> LDS row
    // l>>3 of an 8-row group, physical 16B chunk l&7; fetches LOGICAL
    // chunk (l&7)^(l>>3) (XOR swizzle; 0 conflicts verified R2/R3).
    const int rsub = lane >> 3;
    const int jchunk = (lane & 7) ^ rsub;
    const char* gA = (const char*)(Xb + (size_t)(rowB + rsub) * K) + jchunk * 16;
    const char* gB = (const char*)(Xb + (size_t)(colB + rsub) * K) + jchunk * 16;
    char* const myLds = sMem[wave];
    const size_t g8 = (size_t)8 * K * 2;  // 8 rows, bytes

    // Fragment read offsets: row m = si*16 + lc; kk=0 logical chunk q,
    // kk=1 logical chunk 4+q; physical = logical ^ (row&7) = ^ (lc&7).
    const int xo0 = ((q ^ (lc & 7)) * 16);
    const int xo1 = (((4 + q) ^ (lc & 7)) * 16);

#define STAGE(ktel, par)                                              \
    {                                                                 \
        const size_t go = (size_t)(ktel) * 2;                         \
        char* dA = myLds + (par) * 8192;                              \
        char* dB = myLds + 16384 + (par) * 8192;                      \
        _Pragma("unroll") for (int i2 = 0; i2 < 8; i2++)              \
            gl2lds16(gA + go + i2 * g8, dA + i2 * 1024);              \
        _Pragma("unroll") for (int i2 = 0; i2 < 8; i2++)              \
            gl2lds16(gB + go + i2 * g8, dB + i2 * 1024);              \
    }

    const int nit = K >> 6;  // BK=64
    STAGE(0, 0);
    for (int it = 0; it < nit; it++) {
        if (it + 1 < nit) {
            STAGE((it + 1) * 64, (it + 1) & 1);
            // Wait for tile `it`'s 16 loads; the 16 just issued stay out.
            asm volatile("s_waitcnt vmcnt(16)" ::: "memory");
        } else {
            asm volatile("s_waitcnt vmcnt(0)" ::: "memory");
        }
        const char* cA = myLds + (it & 1) * 8192;
        const char* cB = myLds + 16384 + (it & 1) * 8192;
#pragma unroll
        for (int kk = 0; kk < 2; kk++) {
            const int xo = kk ? xo1 : xo0;
            bf16x8 af[4], bfr[4];
#pragma unroll
            for (int b = 0; b < 4; b++) {
                af[b]  = *(const bf16x8*)(cA + (b * 16 + lc) * 128 + xo);
                bfr[b] = *(const bf16x8*)(cB + (b * 16 + lc) * 128 + xo);
            }
#pragma unroll
            for (int si = 0; si < 4; si++)
#pragma unroll
                for (int sj = 0; sj < 4; sj++)
                    acc[si][sj] = __builtin_amdgcn_mfma_f32_16x16x32_bf16(
                        af[si], bfr[sj], acc[si][sj], 0, 0, 0);
        }
    }

    // Wave-local epilogue. C/D layout: col = lc, row = q*4 + reg.
    int yc[4]; float nc[4];
#pragma unroll
    for (int sj = 0; sj < 4; sj++) {
        yc[sj] = Y[colB + sj * 16 + lc];
        nc[sj] = nrm[colB + sj * 16 + lc];
    }
    int yr[4][4]; float nr[4][4];
#pragma unroll
    for (int si = 0; si < 4; si++)
#pragma unroll
        for (int rr = 0; rr < 4; rr++) {
            yr[si][rr] = Y[rowB + si * 16 + q * 4 + rr];
            nr[si][rr] = nrm[rowB + si * 16 + q * 4 + rr];
        }

    float rmx[4][4], rmn[4][4], cmx[4], cmn[4];
#pragma unroll
    for (int i = 0; i < 4; i++) {
        cmx[i] = -1.0f; cmn[i] = BIGF;
#pragma unroll
        for (int rr = 0; rr < 4; rr++) { rmx[i][rr] = -1.0f; rmn[i][rr] = BIGF; }
    }

#pragma unroll
    for (int sj = 0; sj < 4; sj++)
#pragma unroll
        for (int si = 0; si < 4; si++)
#pragma unroll
            for (int rr = 0; rr < 4; rr++) {
                float d2 = nr[si][rr] + nc[sj] - 2.0f * acc[si][sj][rr];
                float d = sqrtf(fmaxf(d2, 0.0f));
                bool same = (yr[si][rr] == yc[sj]);
                float dp = same ? d : -1.0f;
                float dn = same ? BIGF : d;
                rmx[si][rr] = fmaxf(rmx[si][rr], dp);
                rmn[si][rr] = fminf(rmn[si][rr], dn);
                cmx[sj] = fmaxf(cmx[sj], dp);
                cmn[sj] = fminf(cmn[sj], dn);
            }

    // Row-side: butterfly across the 16 lanes of a quad (same row, 16 cols),
    // then lc==0 lanes hold row si*16+q*4+rr. Non-negative floats: uint cmp
    // == float cmp; clamp max to 0 (true dist_ap >= 0 via diagonal).
#pragma unroll
    for (int si = 0; si < 4; si++)
#pragma unroll
        for (int rr = 0; rr < 4; rr++) {
            float mx = rmx[si][rr], mn = rmn[si][rr];
            for (int off = 1; off < 16; off <<= 1) {
                mx = fmaxf(mx, __shfl_xor(mx, off, 64));
                mn = fminf(mn, __shfl_xor(mn, off, 64));
            }
            if (lc == 0) {
                const int rdst = rowB + si * 16 + q * 4 + rr;
                atomicMax(&ap[rdst], __float_as_uint(fmaxf(mx, 0.0f)));
                atomicMin(&an[rdst], __float_as_uint(mn));
            }
        }

    // Col-side: reduce across quads (different rows, same col), q==0 lanes
    // hold col sj*16+lc.
#pragma unroll
    for (int sj = 0; sj < 4; sj++) {
        float mx = cmx[sj], mn = cmn[sj];
        mx = fmaxf(mx, __shfl_xor(mx, 16, 64));
        mn = fminf(mn, __shfl_xor(mn, 16, 64));
        mx = fmaxf(mx, __shfl_xor(mx, 32, 64));
        mn = fminf(mn, __shfl_xor(mn, 32, 64));
        if (q == 0) {
            const int cdst = colB + sj * 16 + lc;
            atomicMax(&ap[cdst], __float_as_uint(fmaxf(mx, 0.0f)));
            atomicMin(&an[cdst], __float_as_uint(mn));
        }
    }

    // Last block computes the loss (release fence before counter increment;
    // acquire fence + agent-scope atomic loads in the last block).
    __syncthreads();
    if (tid == 0) {
        __threadfence();
        s_done = atomicAdd(cnt, 1u);
    }
    __syncthreads();
    if (s_done == gridDim.x - 1) {
        __threadfence();
        float s = 0.0f;
        for (int i = tid; i < N; i += 128) {
            unsigned ua = __hip_atomic_load(&ap[i], __ATOMIC_RELAXED,
                                            __HIP_MEMORY_SCOPE_AGENT);
            unsigned ub = __hip_atomic_load(&an[i], __ATOMIC_RELAXED,
                                            __HIP_MEMORY_SCOPE_AGENT);
            s += fmaxf(__uint_as_float(ua) - __uint_as_float(ub) + MARGIN, 0.0f);
        }
        for (int off = 32; off > 0; off >>= 1) s += __shfl_xor(s, off, 64);
        if (lane == 0) lsum[wave] = s;
        __syncthreads();
        if (tid == 0) out[0] = (lsum[0] + lsum[1]) / (float)N;
    }
}

extern "C" void kernel_launch(void* const* d_in, const int* in_sizes, int n_in,
                              void* d_out, int out_size, void* d_ws, size_t ws_size,
                              hipStream_t stream) {
    const float* X = (const float*)d_in[0];
    const int* Y = (const int*)d_in[1];
    float* out = (float*)d_out;
    const int N = in_sizes[1];          // 4096
    const int K = in_sizes[0] / N;      // 2048

    char* ws = (char*)d_ws;
    __hip_bfloat16* Xb = (__hip_bfloat16*)ws;                       // N*K*2 bytes
    float* nrm = (float*)(ws + (size_t)N * K * sizeof(__hip_bfloat16));
    unsigned* ap = (unsigned*)((char*)nrm + (size_t)N * 4);
    unsigned* an = (unsigned*)((char*)ap + (size_t)N * 4);
    unsigned* cnt = (unsigned*)((char*)an + (size_t)N * 4);

    convert_norm_kernel<<<N / 4, 256, 0, stream>>>(X, Xb, nrm, ap, an, cnt, K);
    const int NB = N / 64;
    const int ntiles = NB * (NB + 1) / 2;   // 64x64 upper-triangle tiles
    const int nblocks = (ntiles + 1) / 2;   // 2 wave-tiles per block
    gemm_reduce_kernel<<<nblocks, 128, 0, stream>>>(Xb, nrm, Y, ap, an, cnt,
                                                    out, N, K);
}

// Round 7
// 147.816 us; speedup vs baseline: 1.6749x; 1.3974x over previous
//
#include <hip/hip_runtime.h>
#include <hip/hip_bf16.h>
#include <hip/hip_fp8.h>

typedef __attribute__((ext_vector_type(4))) int i32x4;
typedef __attribute__((ext_vector_type(8))) int i32x8;
typedef __attribute__((ext_vector_type(16))) float f32x16;

#define MARGIN 0.3f
#define BIGF 3.0e38f

__device__ __forceinline__ void gl2lds16(const void* g, void* l) {
    __builtin_amdgcn_global_load_lds(
        (const __attribute__((address_space(1))) void*)g,
        (__attribute__((address_space(3))) void*)l,
        16, 0, 0);
}

// Wave-per-row convert: fp32 -> fp8 e4m3 (OCP) cast, fp32 row norm of the
// fp8-ROUNDED values (consistent with MFMA dots -> exact diagonal), init
// ap/an/cnt. 4 rows per 256-thread block.
__global__ __launch_bounds__(256) void convert_norm_kernel(
    const float* __restrict__ X, unsigned char* __restrict__ Xq,
    float* __restrict__ nrm, unsigned* __restrict__ ap,
    unsigned* __restrict__ an, unsigned* __restrict__ cnt, int K) {
    const int wave = threadIdx.x >> 6, lane = threadIdx.x & 63;
    const int row = blockIdx.x * 4 + wave;
    const float* xr = X + (size_t)row * K;
    unsigned char* xqr = Xq + (size_t)row * K;
    float s = 0.0f;
    for (int c = lane * 8; c < K; c += 64 * 8) {
        float4 v0 = *(const float4*)(xr + c);
        float4 v1 = *(const float4*)(xr + c + 4);
        float f[8] = {v0.x, v0.y, v0.z, v0.w, v1.x, v1.y, v1.z, v1.w};
        union { unsigned char b[8]; uint2 u; } p;
#pragma unroll
        for (int i = 0; i < 8; i++) {
            __hip_fp8_e4m3 q(f[i]);       // OCP e4m3, RNE+saturate
            p.b[i] = q.__x;
            float d = (float)q;           // decoded value
            s += d * d;
        }
        *(uint2*)(xqr + c) = p.u;
    }
    for (int off = 32; off > 0; off >>= 1) s += __shfl_xor(s, off, 64);
    if (lane == 0) {
        nrm[row] = s;
        ap[row] = 0u;           // dist_ap >= 0 always (self is a positive)
        an[row] = 0x7F800000u;  // +inf
        if (row == 0) *cnt = 0u;
    }
}

// MX-fp8 GEMM-reduce: G = Xq * Xq^T via mfma_scale_f32_32x32x64_f8f6f4
// with unit scales (0x7F = 2^0) -> plain fp8 matmul at 2x bf16 rate and
// K=64/instruction. Upper-triangle 64x128 tiles (1056 blocks), 4 waves,
// wave tile 64x32 (2 subtiles of 32x32). BK=128 fp8 = 128 B/row -> same
// LDS row geometry + XOR swizzle as R2/R3 (phys 16B chunk = logical ^
// (row&7); measured 0 conflicts), but HALF the staged bytes, HALF the
// barriers (16 iters), and half the fragment LDS reads per FLOP.
// A-frag (32x32x64): row = lane&31, k = (lane>>5)*32 + [0..32) contiguous
// bytes of an Xq row. C/D: col = lane&31, row = (reg&3)+8*(reg>>2)+
// 4*(lane>>5) [m74/m101]. Epilogue: row-side butterfly over lane&31 +
// cross-wave LDS combine; col-side in-register + xor-32 merge; monotone
// uint atomics; LAST block computes the loss.
__global__ __launch_bounds__(256) void gemm_reduce_kernel(
    const unsigned char* __restrict__ Xq, const float* __restrict__ nrm,
    const int* __restrict__ Y, unsigned* __restrict__ ap,
    unsigned* __restrict__ an, unsigned* __restrict__ cnt,
    float* __restrict__ out, int N, int K) {
    __shared__ __align__(16) unsigned char sA[64 * 128];   // 8 KB
    __shared__ __align__(16) unsigned char sB[128 * 128];  // 16 KB
    __shared__ int sYr[64], sYc[128];
    __shared__ float sNr[64], sNc[128];
    __shared__ float redmax[4][64], redmin[4][64];
    __shared__ float lsum[4];
    __shared__ unsigned s_done;

    const int tid = threadIdx.x;
    const int wave = tid >> 6;
    const int lane = tid & 63;
    const int m = lane & 31;   // row within 32x32 subtile / col within wave tile
    const int h = lane >> 5;   // k-half (inputs) / row-group (outputs)

    // Decode (col-block j, row-block r): blocks for col j are j(j+1)..(j+1)(j+2).
    int j = 0;
    {
        const int b = blockIdx.x;
        while ((j + 1) * (j + 2) <= b) j++;
    }
    const int r = blockIdx.x - j * (j + 1);  // 0..2j+1
    const int rowBase = r * 64;
    const int colBase = j * 128;

    if (tid < 64) {
        sYr[tid] = Y[rowBase + tid];
        sNr[tid] = nrm[rowBase + tid];
    } else if (tid < 192) {
        int t = tid - 64;
        sYc[t] = Y[colBase + t];
        sNc[t] = nrm[colBase + t];
    }

    f32x16 acc[2];
#pragma unroll
    for (int si = 0; si < 2; si++)
#pragma unroll
        for (int rr = 0; rr < 16; rr++) acc[si][rr] = 0.0f;

    // Staging (R3 lane math, fp8 strides): lane l -> LDS row l>>3 of an
    // 8-row group, physical 16B chunk l&7, fetching LOGICAL chunk
    // (l&7)^(l>>3) so phys = logical ^ (row&7).
    const int rsub = lane >> 3;
    const int jchunk = (lane & 7) ^ rsub;
    const unsigned char* gA = Xq + (size_t)(rowBase + wave * 16 + rsub) * K + jchunk * 16;
    const unsigned char* gB = Xq + (size_t)(colBase + wave * 32 + rsub) * K + jchunk * 16;
    unsigned char* lA = sA + wave * 2048;  // 16 rows * 128 B
    unsigned char* lB = sB + wave * 4096;  // 32 rows * 128 B
    const size_t g8 = (size_t)8 * K;       // 8 rows, bytes

    const int e = m & 7;  // unswizzle key: row&7 = m&7 (rows offset by mult of 32)
    const int nit = K >> 7;  // BK=128

    for (int it = 0; it < nit; it++) {
        const size_t go = (size_t)it * 128;  // 128 k-elems * 1 B
        gl2lds16(gA + go, lA);
        gl2lds16(gA + go + g8, lA + 1024);
        gl2lds16(gB + go, lB);
        gl2lds16(gB + go + g8, lB + 1024);
        gl2lds16(gB + go + 2 * g8, lB + 2048);
        gl2lds16(gB + go + 3 * g8, lB + 3072);
        __syncthreads();  // drains vmcnt for gl2lds

#pragma unroll
        for (int s = 0; s < 2; s++) {  // two k64 steps per BK=128
            const int c0 = s * 4 + h * 2;  // logical 16B chunk of this k-half
            i32x8 af[2], bf;
#pragma unroll
            for (int si = 0; si < 2; si++) {
                const unsigned char* base = sA + (si * 32 + m) * 128;
                i32x4 lo = *(const i32x4*)(base + ((c0 ^ e) * 16));
                i32x4 hi = *(const i32x4*)(base + (((c0 + 1) ^ e) * 16));
                af[si] = __builtin_shufflevector(lo, hi, 0, 1, 2, 3, 4, 5, 6, 7);
            }
            {
                const unsigned char* base = sB + (wave * 32 + m) * 128;
                i32x4 lo = *(const i32x4*)(base + ((c0 ^ e) * 16));
                i32x4 hi = *(const i32x4*)(base + (((c0 + 1) ^ e) * 16));
                bf = __builtin_shufflevector(lo, hi, 0, 1, 2, 3, 4, 5, 6, 7);
            }
#pragma unroll
            for (int si = 0; si < 2; si++)
                acc[si] = __builtin_amdgcn_mfma_scale_f32_32x32x64_f8f6f4(
                    af[si], bf, acc[si], 0 /*A fmt fp8*/, 0 /*B fmt fp8*/,
                    0, 127 /*scale A = 2^0*/, 0, 127 /*scale B = 2^0*/);
        }
        __syncthreads();
    }

    // Epilogue. C/D: col = m (within wave's 32 cols), row64 = si*32 +
    // (reg&3) + 8*(reg>>2) + 4*h.
    const int col = wave * 32 + m;
    const int yc = sYc[col];
    const float ncol = sNc[col];
    float cmx = -1.0f, cmn = BIGF;

#pragma unroll
    for (int si = 0; si < 2; si++)
#pragma unroll
        for (int reg = 0; reg < 16; reg++) {
            const int row64 = si * 32 + (reg & 3) + 8 * (reg >> 2) + 4 * h;
            float d2 = sNr[row64] + ncol - 2.0f * acc[si][reg];
            float d = sqrtf(fmaxf(d2, 0.0f));
            bool same = (sYr[row64] == yc);
            float dp = same ? d : -1.0f;
            float dn = same ? BIGF : d;
            cmx = fmaxf(cmx, dp);
            cmn = fminf(cmn, dn);
            // Row-side: reduce over the 32 col-lanes (offsets 1..16 keep h).
            float mx = dp, mn = dn;
            for (int off = 1; off < 32; off <<= 1) {
                mx = fmaxf(mx, __shfl_xor(mx, off, 64));
                mn = fminf(mn, __shfl_xor(mn, off, 64));
            }
            if (m == 0) {  // lanes 0 (h=0) and 32 (h=1): disjoint row64 sets
                redmax[wave][row64] = mx;
                redmin[wave][row64] = mn;
            }
        }

    // Col-side: merge the two h row-groups; lanes h==0 hold their col.
    cmx = fmaxf(cmx, __shfl_xor(cmx, 32, 64));
    cmn = fminf(cmn, __shfl_xor(cmn, 32, 64));
    if (h == 0) {
        atomicMax(&ap[colBase + col], __float_as_uint(fmaxf(cmx, 0.0f)));
        atomicMin(&an[colBase + col], __float_as_uint(cmn));
    }
    __syncthreads();

    // Row-side: combine 4 waves (non-negative floats: uint cmp == float cmp;
    // clamp max to 0 since true dist_ap >= 0 via the diagonal self-pair).
    if (tid < 64) {
        float mx = fmaxf(fmaxf(redmax[0][tid], redmax[1][tid]),
                         fmaxf(redmax[2][tid], redmax[3][tid]));
        float mn = fminf(fminf(redmin[0][tid], redmin[1][tid]),
                         fminf(redmin[2][tid], redmin[3][tid]));
        atomicMax(&ap[rowBase + tid], __float_as_uint(fmaxf(mx, 0.0f)));
        atomicMin(&an[rowBase + tid], __float_as_uint(mn));
    }

    // Last block computes the loss (release fence before counter increment;
    // acquire fence + agent-scope atomic loads in the last block).
    __syncthreads();
    if (tid == 0) {
        __threadfence();
        s_done = atomicAdd(cnt, 1u);
    }
    __syncthreads();
    if (s_done == gridDim.x - 1) {
        __threadfence();
        float s = 0.0f;
        for (int i = tid; i < N; i += 256) {
            unsigned ua = __hip_atomic_load(&ap[i], __ATOMIC_RELAXED,
                                            __HIP_MEMORY_SCOPE_AGENT);
            unsigned ub = __hip_atomic_load(&an[i], __ATOMIC_RELAXED,
                                            __HIP_MEMORY_SCOPE_AGENT);
            s += fmaxf(__uint_as_float(ua) - __uint_as_float(ub) + MARGIN, 0.0f);
        }
        for (int off = 32; off > 0; off >>= 1) s += __shfl_xor(s, off, 64);
        if (lane == 0) lsum[wave] = s;
        __syncthreads();
        if (tid == 0)
            out[0] = (lsum[0] + lsum[1] + lsum[2] + lsum[3]) / (float)N;
    }
}

extern "C" void kernel_launch(void* const* d_in, const int* in_sizes, int n_in,
                              void* d_out, int out_size, void* d_ws, size_t ws_size,
                              hipStream_t stream) {
    const float* X = (const float*)d_in[0];
    const int* Y = (const int*)d_in[1];
    float* out = (float*)d_out;
    const int N = in_sizes[1];          // 4096
    const int K = in_sizes[0] / N;      // 2048

    char* ws = (char*)d_ws;
    unsigned char* Xq = (unsigned char*)ws;                         // N*K bytes
    float* nrm = (float*)(ws + (size_t)N * K);
    unsigned* ap = (unsigned*)((char*)nrm + (size_t)N * 4);
    unsigned* an = (unsigned*)((char*)ap + (size_t)N * 4);
    unsigned* cnt = (unsigned*)((char*)an + (size_t)N * 4);

    convert_norm_kernel<<<N / 4, 256, 0, stream>>>(X, Xq, nrm, ap, an, cnt, K);
    const int NB = N / 128;
    const int nblocks = NB * (NB + 1);  // 64x128 tiles covering the triangle
    gemm_reduce_kernel<<<nblocks, 256, 0, stream>>>(Xq, nrm, Y, ap, an, cnt,
                                                    out, N, K);
}

// Round 8
// 145.162 us; speedup vs baseline: 1.7055x; 1.0183x over previous
//
#include <hip/hip_runtime.h>
#include <hip/hip_bf16.h>
#include <hip/hip_fp8.h>

typedef __attribute__((ext_vector_type(4))) int i32x4;
typedef __attribute__((ext_vector_type(8))) int i32x8;
typedef __attribute__((ext_vector_type(16))) float f32x16;

#define MARGIN 0.3f
#define BIGF 3.0e38f

__device__ __forceinline__ void gl2lds16(const void* g, void* l) {
    __builtin_amdgcn_global_load_lds(
        (const __attribute__((address_space(1))) void*)g,
        (__attribute__((address_space(3))) void*)l,
        16, 0, 0);
}

// Wave-per-row convert: fp32 -> fp8 e4m3 (OCP) cast, fp32 row norm of the
// fp8-ROUNDED values (consistent with MFMA dots -> exact diagonal), init
// ap/an/cnt. 4 rows per 256-thread block.
__global__ __launch_bounds__(256) void convert_norm_kernel(
    const float* __restrict__ X, unsigned char* __restrict__ Xq,
    float* __restrict__ nrm, unsigned* __restrict__ ap,
    unsigned* __restrict__ an, unsigned* __restrict__ cnt, int K) {
    const int wave = threadIdx.x >> 6, lane = threadIdx.x & 63;
    const int row = blockIdx.x * 4 + wave;
    const float* xr = X + (size_t)row * K;
    unsigned char* xqr = Xq + (size_t)row * K;
    float s = 0.0f;
    for (int c = lane * 8; c < K; c += 64 * 8) {
        float4 v0 = *(const float4*)(xr + c);
        float4 v1 = *(const float4*)(xr + c + 4);
        float f[8] = {v0.x, v0.y, v0.z, v0.w, v1.x, v1.y, v1.z, v1.w};
        union { unsigned char b[8]; uint2 u; } p;
#pragma unroll
        for (int i = 0; i < 8; i++) {
            __hip_fp8_e4m3 q(f[i]);       // OCP e4m3, RNE+saturate
            p.b[i] = q.__x;
            float d = (float)q;           // decoded value
            s += d * d;
        }
        *(uint2*)(xqr + c) = p.u;
    }
    for (int off = 32; off > 0; off >>= 1) s += __shfl_xor(s, off, 64);
    if (lane == 0) {
        nrm[row] = s;
        ap[row] = 0u;           // dist_ap >= 0 always (self is a positive)
        an[row] = 0x7F800000u;  // +inf
        if (row == 0) *cnt = 0u;
    }
}

// MX-fp8 GEMM-reduce, BK=256 (8 iterations at K=2048): halves the barrier/
// drain count vs R7 and doubles MFMA work per drain (8 mfma_scale/wave/iter).
// Upper-triangle 64x128 tiles (1056 blocks), 4 waves, wave tile 64x32.
// LDS rows are 256 B = 16 chunks of 16 B, XOR-swizzled: phys chunk =
// logical ^ (row&7) (xor hits only low 3 bits so chunks stay in their
// k64 half). Staging covers 4 rows per gl2lds; the xor key for rows
// g..g+3 is (g&4) + (lane>>4). Everything else is R7-verified: tile
// decode, mfma_scale_f32_32x32x64_f8f6f4 with unit scales (0x7F), C/D map
// col=lane&31 / row=(reg&3)+8*(reg>>2)+4*(lane>>5), epilogue reductions,
// monotone uint atomics, fused last-block loss.
__global__ __launch_bounds__(256) void gemm_reduce_kernel(
    const unsigned char* __restrict__ Xq, const float* __restrict__ nrm,
    const int* __restrict__ Y, unsigned* __restrict__ ap,
    unsigned* __restrict__ an, unsigned* __restrict__ cnt,
    float* __restrict__ out, int N, int K) {
    __shared__ __align__(16) unsigned char sA[64 * 256];   // 16 KB
    __shared__ __align__(16) unsigned char sB[128 * 256];  // 32 KB
    __shared__ int sYr[64], sYc[128];
    __shared__ float sNr[64], sNc[128];
    __shared__ float redmax[4][64], redmin[4][64];
    __shared__ float lsum[4];
    __shared__ unsigned s_done;

    const int tid = threadIdx.x;
    const int wave = tid >> 6;
    const int lane = tid & 63;
    const int m = lane & 31;   // row within 32x32 subtile / col within wave tile
    const int h = lane >> 5;   // k-half (inputs) / row-group (outputs)

    // Decode (col-block j, row-block r): blocks for col j are j(j+1)..(j+1)(j+2).
    int j = 0;
    {
        const int b = blockIdx.x;
        while ((j + 1) * (j + 2) <= b) j++;
    }
    const int r = blockIdx.x - j * (j + 1);  // 0..2j+1
    const int rowBase = r * 64;
    const int colBase = j * 128;

    if (tid < 64) {
        sYr[tid] = Y[rowBase + tid];
        sNr[tid] = nrm[rowBase + tid];
    } else if (tid < 192) {
        int t = tid - 64;
        sYc[t] = Y[colBase + t];
        sNc[t] = nrm[colBase + t];
    }

    f32x16 acc[2];
#pragma unroll
    for (int si = 0; si < 2; si++)
#pragma unroll
        for (int rr = 0; rr < 16; rr++) acc[si][rr] = 0.0f;

    // Staging: each gl2lds covers 4 rows of 256 B. Lane l -> LDS row l>>4,
    // physical chunk l&15; fetches LOGICAL chunk (l&15) ^ ((g&4)+(l>>4))
    // for row-group g (so phys = logical ^ (row&7)).
    const int rsub = lane >> 4;  // row within 4-row group
    const int oe = (((lane & 15) ^ rsub) * 16);        // g % 8 == 0 groups
    const int oo = (((lane & 15) ^ (4 + rsub)) * 16);  // g % 8 == 4 groups
    const unsigned char* gAb = Xq + (size_t)(rowBase + wave * 16 + rsub) * K;
    const unsigned char* gBb = Xq + (size_t)(colBase + wave * 32 + rsub) * K;
    unsigned char* lA = sA + wave * 4096;  // 16 rows * 256 B
    unsigned char* lB = sB + wave * 8192;  // 32 rows * 256 B
    const size_t g4 = (size_t)4 * K;       // 4 rows, bytes

    const int e = m & 7;     // unswizzle key: row&7 = m&7 (row offsets are mult. of 32)
    const int nit = K >> 8;  // BK=256

    for (int it = 0; it < nit; it++) {
        const size_t go = (size_t)it * 256;  // 256 k-elems * 1 B
#pragma unroll
        for (int gi = 0; gi < 4; gi++)
            gl2lds16(gAb + go + gi * g4 + ((gi & 1) ? oo : oe), lA + gi * 1024);
#pragma unroll
        for (int gi = 0; gi < 8; gi++)
            gl2lds16(gBb + go + gi * g4 + ((gi & 1) ? oo : oe), lB + gi * 1024);
        __syncthreads();  // drains vmcnt for gl2lds

#pragma unroll
        for (int s = 0; s < 4; s++) {  // four k64 steps per BK=256
            const int c0 = s * 4 + h * 2;  // logical 16B chunk of this k-half
            i32x8 af[2], bf;
#pragma unroll
            for (int si = 0; si < 2; si++) {
                const unsigned char* base = sA + (si * 32 + m) * 256;
                i32x4 lo = *(const i32x4*)(base + ((c0 ^ e) * 16));
                i32x4 hi = *(const i32x4*)(base + (((c0 + 1) ^ e) * 16));
                af[si] = __builtin_shufflevector(lo, hi, 0, 1, 2, 3, 4, 5, 6, 7);
            }
            {
                const unsigned char* base = sB + (wave * 32 + m) * 256;
                i32x4 lo = *(const i32x4*)(base + ((c0 ^ e) * 16));
                i32x4 hi = *(const i32x4*)(base + (((c0 + 1) ^ e) * 16));
                bf = __builtin_shufflevector(lo, hi, 0, 1, 2, 3, 4, 5, 6, 7);
            }
#pragma unroll
            for (int si = 0; si < 2; si++)
                acc[si] = __builtin_amdgcn_mfma_scale_f32_32x32x64_f8f6f4(
                    af[si], bf, acc[si], 0 /*A fmt fp8*/, 0 /*B fmt fp8*/,
                    0, 127 /*scale A = 2^0*/, 0, 127 /*scale B = 2^0*/);
        }
        __syncthreads();
    }

    // Epilogue. C/D: col = m (within wave's 32 cols), row64 = si*32 +
    // (reg&3) + 8*(reg>>2) + 4*h.
    const int col = wave * 32 + m;
    const int yc = sYc[col];
    const float ncol = sNc[col];
    float cmx = -1.0f, cmn = BIGF;

#pragma unroll
    for (int si = 0; si < 2; si++)
#pragma unroll
        for (int reg = 0; reg < 16; reg++) {
            const int row64 = si * 32 + (reg & 3) + 8 * (reg >> 2) + 4 * h;
            float d2 = sNr[row64] + ncol - 2.0f * acc[si][reg];
            float d = sqrtf(fmaxf(d2, 0.0f));
            bool same = (sYr[row64] == yc);
            float dp = same ? d : -1.0f;
            float dn = same ? BIGF : d;
            cmx = fmaxf(cmx, dp);
            cmn = fminf(cmn, dn);
            // Row-side: reduce over the 32 col-lanes (offsets 1..16 keep h).
            float mx = dp, mn = dn;
            for (int off = 1; off < 32; off <<= 1) {
                mx = fmaxf(mx, __shfl_xor(mx, off, 64));
                mn = fminf(mn, __shfl_xor(mn, off, 64));
            }
            if (m == 0) {  // lanes 0 (h=0) and 32 (h=1): disjoint row64 sets
                redmax[wave][row64] = mx;
                redmin[wave][row64] = mn;
            }
        }

    // Col-side: merge the two h row-groups; lanes h==0 hold their col.
    cmx = fmaxf(cmx, __shfl_xor(cmx, 32, 64));
    cmn = fminf(cmn, __shfl_xor(cmn, 32, 64));
    if (h == 0) {
        atomicMax(&ap[colBase + col], __float_as_uint(fmaxf(cmx, 0.0f)));
        atomicMin(&an[colBase + col], __float_as_uint(cmn));
    }
    __syncthreads();

    // Row-side: combine 4 waves (non-negative floats: uint cmp == float cmp;
    // clamp max to 0 since true dist_ap >= 0 via the diagonal self-pair).
    if (tid < 64) {
        float mx = fmaxf(fmaxf(redmax[0][tid], redmax[1][tid]),
                         fmaxf(redmax[2][tid], redmax[3][tid]));
        float mn = fminf(fminf(redmin[0][tid], redmin[1][tid]),
                         fminf(redmin[2][tid], redmin[3][tid]));
        atomicMax(&ap[rowBase + tid], __float_as_uint(fmaxf(mx, 0.0f)));
        atomicMin(&an[rowBase + tid], __float_as_uint(mn));
    }

    // Last block computes the loss (release fence before counter increment;
    // acquire fence + agent-scope atomic loads in the last block).
    __syncthreads();
    if (tid == 0) {
        __threadfence();
        s_done = atomicAdd(cnt, 1u);
    }
    __syncthreads();
    if (s_done == gridDim.x - 1) {
        __threadfence();
        float s = 0.0f;
        for (int i = tid; i < N; i += 256) {
            unsigned ua = __hip_atomic_load(&ap[i], __ATOMIC_RELAXED,
                                            __HIP_MEMORY_SCOPE_AGENT);
            unsigned ub = __hip_atomic_load(&an[i], __ATOMIC_RELAXED,
                                            __HIP_MEMORY_SCOPE_AGENT);
            s += fmaxf(__uint_as_float(ua) - __uint_as_float(ub) + MARGIN, 0.0f);
        }
        for (int off = 32; off > 0; off >>= 1) s += __shfl_xor(s, off, 64);
        if (lane == 0) lsum[wave] = s;
        __syncthreads();
        if (tid == 0)
            out[0] = (lsum[0] + lsum[1] + lsum[2] + lsum[3]) / (float)N;
    }
}

extern "C" void kernel_launch(void* const* d_in, const int* in_sizes, int n_in,
                              void* d_out, int out_size, void* d_ws, size_t ws_size,
                              hipStream_t stream) {
    const float* X = (const float*)d_in[0];
    const int* Y = (const int*)d_in[1];
    float* out = (float*)d_out;
    const int N = in_sizes[1];          // 4096
    const int K = in_sizes[0] / N;      // 2048

    char* ws = (char*)d_ws;
    unsigned char* Xq = (unsigned char*)ws;                         // N*K bytes
    float* nrm = (float*)(ws + (size_t)N * K);
    unsigned* ap = (unsigned*)((char*)nrm + (size_t)N * 4);
    unsigned* an = (unsigned*)((char*)ap + (size_t)N * 4);
    unsigned* cnt = (unsigned*)((char*)an + (size_t)N * 4);

    convert_norm_kernel<<<N / 4, 256, 0, stream>>>(X, Xq, nrm, ap, an, cnt, K);
    const int NB = N / 128;
    const int nblocks = NB * (NB + 1);  // 64x128 tiles covering the triangle
    gemm_reduce_kernel<<<nblocks, 256, 0, stream>>>(Xq, nrm, Y, ap, an, cnt,
                                                    out, N, K);
}